// Round 1
// 9995.914 us; speedup vs baseline: 1.2650x; 1.2650x over previous
//
#include <hip/hip_runtime.h>

#define N_BATCH 32768
#define N_IMG   5
#define DIM     512
#define NKERN   200
#define DCAT    600
#define NROWS   (N_BATCH * N_IMG)   // 163840
#define EPS_FLAG 2e-4f

// ---------------------------------------------------------------------------
// Repack conv weights: w[c][k][d] -> w4T[((k*128 + d4)*200 + c)*4 + j]
// ---------------------------------------------------------------------------
template<int K>
__global__ void transpose_w(const float* __restrict__ w, float* __restrict__ w4T) {
    int g = blockIdx.x * 256 + threadIdx.x;
    if (g >= K * 128 * NKERN) return;
    int k  = g / (128 * NKERN);
    int r  = g - k * (128 * NKERN);
    int d4 = r / NKERN;
    int c  = r - d4 * NKERN;
    float4 v = *(const float4*)(w + (c * K + k) * DIM + d4 * 4);
    ((float4*)w4T)[g] = v;
}

// ---------------------------------------------------------------------------
// fp32 conv block: 4 samples (LDS) x 128 channels (2/thread), 256 threads.
// ---------------------------------------------------------------------------
template<int K, int T>
__global__ __launch_bounds__(256) void conv_relu_max(
    const float* __restrict__ feats, const float* __restrict__ w4T,
    const float* __restrict__ bias, float* __restrict__ cout, int conv_off) {
    __shared__ float fsh[4 * 2560];                       // 40 KB
    int tid = threadIdx.x;
    int tx = tid & 63, ty = tid >> 6;
    const float4* fg = (const float4*)(feats + blockIdx.x * (4 * 2560));
    float4* fs4 = (float4*)fsh;
#pragma unroll
    for (int i = 0; i < 10; i++) fs4[i * 256 + tid] = fg[i * 256 + tid];
    __syncthreads();

    int c0 = blockIdx.y * 128 + tx, c1 = c0 + 64;
    int c0c = min(c0, NKERN - 1), c1c = min(c1, NKERN - 1);
    float acc0[T], acc1[T];
#pragma unroll
    for (int t = 0; t < T; t++) { acc0[t] = 0.f; acc1[t] = 0.f; }
    const float4* fr = (const float4*)(fsh + ty * 2560);
    const float4* w4 = (const float4*)w4T;

    for (int k = 0; k < K; k++) {
#pragma unroll 2
        for (int d4 = 0; d4 < 128; d4++) {
            float4 w0 = w4[(k * 128 + d4) * NKERN + c0c];
            float4 w1 = w4[(k * 128 + d4) * NKERN + c1c];
#pragma unroll
            for (int t = 0; t < T; t++) {
                float4 f = fr[(t + k) * 128 + d4];
                acc0[t] += f.x * w0.x + f.y * w0.y + f.z * w0.z + f.w * w0.w;
                acc1[t] += f.x * w1.x + f.y * w1.y + f.z * w1.z + f.w * w1.w;
            }
        }
    }
    int n = blockIdx.x * 4 + ty;
    if (c0 < NKERN) {
        float b = bias[c0], m = acc0[0] + b;
#pragma unroll
        for (int t = 1; t < T; t++) m = fmaxf(m, acc0[t] + b);
        cout[n * DCAT + conv_off + c0] = fmaxf(m, 0.f);
    }
    if (c1 < NKERN) {
        float b = bias[c1], m = acc1[0] + b;
#pragma unroll
        for (int t = 1; t < T; t++) m = fmaxf(m, acc1[t] + b);
        cout[n * DCAT + conv_off + c1] = fmaxf(m, 0.f);
    }
}

// ---------------------------------------------------------------------------
// fp32 GEMM: C = act(A@B + bias). 64x64 tile, BK=16, 4x4 micro-tile.
// ---------------------------------------------------------------------------
template<int RELU>
__global__ __launch_bounds__(256) void gemm_bias(
    const float* __restrict__ A, const float* __restrict__ B,
    const float* __restrict__ bias, float* __restrict__ C,
    int Kd, int Nc) {
    __shared__ float AsT[16][68];
    __shared__ float Bs[16][68];
    int tid = threadIdx.x;
    int tx = tid & 15, ty = tid >> 4;
    int m0 = blockIdx.x * 64, n0 = blockIdx.y * 64;
    float acc[4][4] = {};
    int arow = tid >> 2, ac4 = tid & 3;
    int br = tid >> 4, bc = tid & 15;

    for (int kk = 0; kk < Kd; kk += 16) {
        int gk = kk + ac4 * 4;
        float4 ga = make_float4(0.f, 0.f, 0.f, 0.f);
        if (gk < Kd) ga = *(const float4*)(A + (size_t)(m0 + arow) * Kd + gk);
        AsT[ac4 * 4 + 0][arow] = ga.x;
        AsT[ac4 * 4 + 1][arow] = ga.y;
        AsT[ac4 * 4 + 2][arow] = ga.z;
        AsT[ac4 * 4 + 3][arow] = ga.w;
        float4 gb = make_float4(0.f, 0.f, 0.f, 0.f);
        int bcol = n0 + bc * 4;
        if (kk + br < Kd && bcol < Nc) gb = *(const float4*)(B + (size_t)(kk + br) * Nc + bcol);
        *(float4*)&Bs[br][bc * 4] = gb;
        __syncthreads();
#pragma unroll
        for (int k2 = 0; k2 < 16; k2++) {
            float4 a4 = *(const float4*)&AsT[k2][ty * 4];
            float4 b4 = *(const float4*)&Bs[k2][tx * 4];
            float a[4] = {a4.x, a4.y, a4.z, a4.w};
            float b[4] = {b4.x, b4.y, b4.z, b4.w};
#pragma unroll
            for (int i = 0; i < 4; i++)
#pragma unroll
                for (int j = 0; j < 4; j++)
                    acc[i][j] += a[i] * b[j];
        }
        __syncthreads();
    }
    int cb = n0 + tx * 4;
    if (cb < Nc) {
        float4 bs = *(const float4*)(bias + cb);
#pragma unroll
        for (int i = 0; i < 4; i++) {
            size_t row = m0 + ty * 4 + i;
            float4 v;
            v.x = acc[i][0] + bs.x; v.y = acc[i][1] + bs.y;
            v.z = acc[i][2] + bs.z; v.w = acc[i][3] + bs.w;
            if (RELU) {
                v.x = fmaxf(v.x, 0.f); v.y = fmaxf(v.y, 0.f);
                v.z = fmaxf(v.z, 0.f); v.w = fmaxf(v.w, 0.f);
            }
            *(float4*)(C + row * Nc + cb) = v;
        }
    }
}

// ---------------------------------------------------------------------------
// Fused fc0(+relu)+fcs, fp32. 64 rows x 64 cols per block; col-tile partials.
// ---------------------------------------------------------------------------
__global__ __launch_bounds__(256) void fc0_fcs_partial(
    const float* __restrict__ feats, const float* __restrict__ ci,
    const float* __restrict__ W, const float* __restrict__ b0,
    const float* __restrict__ fw, float* __restrict__ partial) {
    __shared__ float AsT[16][68];
    __shared__ float Bs[16][68];
    __shared__ float red[64][17];
    int tid = threadIdx.x;
    int tx = tid & 15, ty = tid >> 4;
    int m0 = blockIdx.x * 64, n0 = blockIdx.y * 64;
    float acc[4][4] = {};
    int arow = tid >> 2, ac4 = tid & 3;
    int br = tid >> 4, bc = tid & 15;
    int rg = m0 + arow;
    int n = rg / 5, img = rg - n * 5;
    const float* afeat = feats + (size_t)n * (N_IMG * DIM) + (size_t)img * DIM;
    const float* aci   = ci + (size_t)n * DIM - DIM;    // indexed with gk in [512,1024)

    for (int kk = 0; kk < 2 * DIM; kk += 16) {
        int gk = kk + ac4 * 4;
        float4 ga = (gk < DIM) ? *(const float4*)(afeat + gk)
                               : *(const float4*)(aci + gk);
        AsT[ac4 * 4 + 0][arow] = ga.x;
        AsT[ac4 * 4 + 1][arow] = ga.y;
        AsT[ac4 * 4 + 2][arow] = ga.z;
        AsT[ac4 * 4 + 3][arow] = ga.w;
        float4 gb = *(const float4*)(W + (size_t)(kk + br) * DIM + n0 + bc * 4);
        *(float4*)&Bs[br][bc * 4] = gb;
        __syncthreads();
#pragma unroll
        for (int k2 = 0; k2 < 16; k2++) {
            float4 a4 = *(const float4*)&AsT[k2][ty * 4];
            float4 b4 = *(const float4*)&Bs[k2][tx * 4];
            float a[4] = {a4.x, a4.y, a4.z, a4.w};
            float b[4] = {b4.x, b4.y, b4.z, b4.w};
#pragma unroll
            for (int i = 0; i < 4; i++)
#pragma unroll
                for (int j = 0; j < 4; j++)
                    acc[i][j] += a[i] * b[j];
        }
        __syncthreads();
    }
    int cb = n0 + tx * 4;
    float4 b04 = *(const float4*)(b0 + cb);
    float4 fw4 = *(const float4*)(fw + cb);
#pragma unroll
    for (int i = 0; i < 4; i++) {
        float p = 0.f;
        p += fmaxf(acc[i][0] + b04.x, 0.f) * fw4.x;
        p += fmaxf(acc[i][1] + b04.y, 0.f) * fw4.y;
        p += fmaxf(acc[i][2] + b04.z, 0.f) * fw4.z;
        p += fmaxf(acc[i][3] + b04.w, 0.f) * fw4.w;
        red[ty * 4 + i][tx] = p;
    }
    __syncthreads();
    if (tid < 64) {
        float s = 0.f;
#pragma unroll
        for (int x = 0; x < 16; x++) s += red[tid][x];
        partial[(size_t)(m0 + tid) * 8 + blockIdx.y] = s;
    }
}

__global__ void score_finish(const float* __restrict__ partial,
                             const float* __restrict__ fcs_b,
                             float* __restrict__ out) {
    int m = blockIdx.x * 256 + threadIdx.x;
    if (m >= NROWS) return;
    float s = fcs_b[0];
#pragma unroll
    for (int q = 0; q < 8; q++) s += partial[(size_t)m * 8 + q];
    out[m] = s;
}

// ---------------------------------------------------------------------------
// Ranks from fp32 scores; flag groups with any pairwise gap < EPS_FLAG.
// ---------------------------------------------------------------------------
__global__ void flag_rank(const float* __restrict__ out_scores,
                          float* __restrict__ out, int* __restrict__ flags) {
    int n = blockIdx.x * 256 + threadIdx.x;
    if (n >= N_BATCH) return;
    float s[5];
#pragma unroll
    for (int i = 0; i < 5; i++) s[i] = out_scores[n * 5 + i];
    int f = 0;
#pragma unroll
    for (int i = 0; i < 5; i++) {
        int rk = 0;
#pragma unroll
        for (int j = 0; j < 5; j++) {
            rk += (s[j] > s[i]) || (s[j] == s[i] && j < i);
            if (j > i) f |= (fabsf(s[i] - s[j]) < EPS_FLAG);
        }
        out[NROWS + n * 5 + i] = (float)rk;
    }
    flags[n] = f;
}

// ---------------------------------------------------------------------------
// Exact f64 recompute of the full chain for flagged samples. One block/sample.
// Restructured for lane-parallelism over OUTPUT channels:
//  - conv: thread owns a channel, streams contiguous float4 weights,
//    fsh reads are same-address LDS broadcasts. No shuffles.
//  - fc1/fc2: lanes over output channel -> coalesced weight loads,
//    csh/hsh reads are LDS broadcasts. No shuffles.
// Summation order differs from previous version only at the ~1e-15 level.
// ---------------------------------------------------------------------------
__device__ __forceinline__ double dot4d(float4 f, float4 w, double a) {
    a += (double)f.x * (double)w.x;
    a += (double)f.y * (double)w.y;
    a += (double)f.z * (double)w.z;
    a += (double)f.w * (double)w.w;
    return a;
}

__global__ __launch_bounds__(256) void recompute_flagged(
    const float* __restrict__ feats,
    const float* __restrict__ w2, const float* __restrict__ b2,
    const float* __restrict__ w3, const float* __restrict__ b3,
    const float* __restrict__ w5, const float* __restrict__ b5,
    const float* __restrict__ fc1_w, const float* __restrict__ fc1_b,
    const float* __restrict__ fc2_w, const float* __restrict__ fc2_b,
    const float* __restrict__ fc0_w, const float* __restrict__ fc0_b,
    const float* __restrict__ fcs_w, const float* __restrict__ fcs_b,
    const int* __restrict__ flags, float* __restrict__ out) {
    int n = blockIdx.x;
    if (!flags[n]) return;
    __shared__ float  fsh[2560];
    __shared__ double csh[600];
    __shared__ double hsh[600];
    __shared__ double cish[512];
    __shared__ double rred[5][4];
    int tid = threadIdx.x, lane = tid & 63, wave = tid >> 6;

    const float4* fg = (const float4*)(feats + (size_t)n * 2560);
    float4* fs4 = (float4*)fsh;
    for (int i = tid; i < 640; i += 256) fs4[i] = fg[i];
    __syncthreads();

    // ---- conv blocks: thread tid<200 owns channel tid of each K ----
    if (tid < 200) {
        {   // K=2, T=4
            const float* w = w2 + (size_t)tid * 1024;
            double a0 = 0.0, a1 = 0.0, a2 = 0.0, a3 = 0.0;
            for (int i = 0; i < 1024; i += 4) {
                float4 wv = *(const float4*)(w + i);
                a0 = dot4d(*(const float4*)(fsh + i),        wv, a0);
                a1 = dot4d(*(const float4*)(fsh + 512 + i),  wv, a1);
                a2 = dot4d(*(const float4*)(fsh + 1024 + i), wv, a2);
                a3 = dot4d(*(const float4*)(fsh + 1536 + i), wv, a3);
            }
            double b = (double)b2[tid];
            double m = fmax(fmax(a0, a1), fmax(a2, a3)) + b;
            csh[tid] = fmax(m, 0.0);
        }
        {   // K=3, T=3
            const float* w = w3 + (size_t)tid * 1536;
            double a0 = 0.0, a1 = 0.0, a2 = 0.0;
            for (int i = 0; i < 1536; i += 4) {
                float4 wv = *(const float4*)(w + i);
                a0 = dot4d(*(const float4*)(fsh + i),        wv, a0);
                a1 = dot4d(*(const float4*)(fsh + 512 + i),  wv, a1);
                a2 = dot4d(*(const float4*)(fsh + 1024 + i), wv, a2);
            }
            double b = (double)b3[tid];
            csh[200 + tid] = fmax(fmax(fmax(a0, a1), a2) + b, 0.0);
        }
        {   // K=5, T=1 (4 independent chains over j-slots)
            const float* w = w5 + (size_t)tid * 2560;
            double a0 = 0.0, a1 = 0.0, a2 = 0.0, a3 = 0.0;
            for (int i = 0; i < 2560; i += 16) {
                a0 = dot4d(*(const float4*)(fsh + i),      *(const float4*)(w + i),      a0);
                a1 = dot4d(*(const float4*)(fsh + i + 4),  *(const float4*)(w + i + 4),  a1);
                a2 = dot4d(*(const float4*)(fsh + i + 8),  *(const float4*)(w + i + 8),  a2);
                a3 = dot4d(*(const float4*)(fsh + i + 12), *(const float4*)(w + i + 12), a3);
            }
            double b = (double)b5[tid];
            csh[400 + tid] = fmax(((a0 + a1) + (a2 + a3)) + b, 0.0);
        }
    }
    __syncthreads();

    // ---- fc1: lanes over output channel (coalesced weights) ----
#pragma unroll
    for (int c = 0; c < 3; c++) {
        int ch = tid + c * 256;
        if (ch < DCAT) {
            const float* wp = fc1_w + ch;
            double a0 = 0.0, a1 = 0.0;
            for (int k = 0; k < DCAT; k += 2) {
                a0 += csh[k]     * (double)wp[(size_t)k * DCAT];
                a1 += csh[k + 1] * (double)wp[(size_t)(k + 1) * DCAT];
            }
            hsh[ch] = fmax(a0 + a1 + (double)fc1_b[ch], 0.0);
        }
    }
    __syncthreads();

    // ---- fc2 ----
#pragma unroll
    for (int c = 0; c < 2; c++) {
        int ch = tid + c * 256;
        const float* wp = fc2_w + ch;
        double a0 = 0.0, a1 = 0.0;
        for (int k = 0; k < DCAT; k += 2) {
            a0 += hsh[k]     * (double)wp[(size_t)k * DIM];
            a1 += hsh[k + 1] * (double)wp[(size_t)(k + 1) * DIM];
        }
        cish[ch] = a0 + a1 + (double)fc2_b[ch];
    }
    __syncthreads();

    // ---- fc0 + fcs: thread handles cols tid and tid+256 (coalesced) ----
    double acc0[5] = {}, acc1[5] = {};
#pragma unroll 4
    for (int k = 0; k < 512; k++) {
        double w0 = (double)fc0_w[(size_t)k * DIM + tid];
        double w1 = (double)fc0_w[(size_t)k * DIM + tid + 256];
#pragma unroll
        for (int img = 0; img < 5; img++) {
            double z = (double)fsh[img * 512 + k];
            acc0[img] += z * w0; acc1[img] += z * w1;
        }
    }
#pragma unroll 4
    for (int k = 0; k < 512; k++) {
        double w0 = (double)fc0_w[(size_t)(k + 512) * DIM + tid];
        double w1 = (double)fc0_w[(size_t)(k + 512) * DIM + tid + 256];
        double z = cish[k];
#pragma unroll
        for (int img = 0; img < 5; img++) { acc0[img] += z * w0; acc1[img] += z * w1; }
    }
    double b0a = (double)fc0_b[tid], b0b = (double)fc0_b[tid + 256];
    double fwa = (double)fcs_w[tid], fwb = (double)fcs_w[tid + 256];
#pragma unroll
    for (int img = 0; img < 5; img++) {
        double p = fmax(acc0[img] + b0a, 0.0) * fwa + fmax(acc1[img] + b0b, 0.0) * fwb;
#pragma unroll
        for (int o = 32; o >= 1; o >>= 1) p += __shfl_down(p, o, 64);
        if (lane == 0) rred[img][wave] = p;
    }
    __syncthreads();
    if (tid == 0) {
        double sc[5];
#pragma unroll
        for (int img = 0; img < 5; img++)
            sc[img] = rred[img][0] + rred[img][1] + rred[img][2] + rred[img][3]
                    + (double)fcs_b[0];
#pragma unroll
        for (int i = 0; i < 5; i++) {
            int rk = 0;
#pragma unroll
            for (int j = 0; j < 5; j++)
                rk += (sc[j] > sc[i]) || (sc[j] == sc[i] && j < i);
            out[n * 5 + i] = (float)sc[i];
            out[NROWS + n * 5 + i] = (float)rk;
        }
    }
}

// ---------------------------------------------------------------------------
// Workspace layout (bytes):
//   c [N,600] f32 @ 0          : 78,643,200   (later reused: ci [N,512] f32)
//   reg1 @ 78,643,200          : wT repacks (4.1MB) -> h [N,600] f32 (78.6MB)
//                                -> partial [NROWS,8] f32 (5.24MB)
//   flags @ reg1 + 8,388,608   : 131,072
// ---------------------------------------------------------------------------
extern "C" void kernel_launch(void* const* d_in, const int* in_sizes, int n_in,
                              void* d_out, int out_size, void* d_ws, size_t ws_size,
                              hipStream_t stream) {
    (void)in_sizes; (void)n_in; (void)out_size; (void)ws_size;
    const float* feats = (const float*)d_in[0];
    const float* w2    = (const float*)d_in[1];
    const float* b2    = (const float*)d_in[2];
    const float* w3    = (const float*)d_in[3];
    const float* b3    = (const float*)d_in[4];
    const float* w5    = (const float*)d_in[5];
    const float* b5    = (const float*)d_in[6];
    const float* fc1_w = (const float*)d_in[7];
    const float* fc1_b = (const float*)d_in[8];
    const float* fc2_w = (const float*)d_in[9];
    const float* fc2_b = (const float*)d_in[10];
    const float* fc0_w = (const float*)d_in[11];
    const float* fc0_b = (const float*)d_in[12];
    const float* fcs_w = (const float*)d_in[13];
    const float* fcs_b = (const float*)d_in[14];

    char* ws = (char*)d_ws;
    float* c    = (float*)ws;
    float* reg1 = (float*)(ws + 78643200);
    float* w2T = reg1;
    float* w3T = reg1 + 204800;
    float* w5T = reg1 + 512000;
    int* flags = (int*)(ws + 78643200 + 8388608);

    transpose_w<2><<<dim3((2 * 128 * NKERN + 255) / 256), 256, 0, stream>>>(w2, w2T);
    transpose_w<3><<<dim3((3 * 128 * NKERN + 255) / 256), 256, 0, stream>>>(w3, w3T);
    transpose_w<5><<<dim3((5 * 128 * NKERN + 255) / 256), 256, 0, stream>>>(w5, w5T);

    conv_relu_max<2, 4><<<dim3(N_BATCH / 4, 2), 256, 0, stream>>>(feats, w2T, b2, c, 0);
    conv_relu_max<3, 3><<<dim3(N_BATCH / 4, 2), 256, 0, stream>>>(feats, w3T, b3, c, 200);
    conv_relu_max<5, 1><<<dim3(N_BATCH / 4, 2), 256, 0, stream>>>(feats, w5T, b5, c, 400);

    float* h = reg1;                               // overwrites wT (dead)
    gemm_bias<1><<<dim3(N_BATCH / 64, 10), 256, 0, stream>>>(c, fc1_w, fc1_b, h, DCAT, DCAT);

    float* ci = (float*)ws;                        // overwrites c (dead)
    gemm_bias<0><<<dim3(N_BATCH / 64, 8), 256, 0, stream>>>(h, fc2_w, fc2_b, ci, DCAT, DIM);

    float* partial = reg1;                         // overwrites h (dead)
    fc0_fcs_partial<<<dim3(NROWS / 64, 8), 256, 0, stream>>>(feats, ci, fc0_w, fc0_b, fcs_w, partial);

    float* out = (float*)d_out;
    score_finish<<<dim3((NROWS + 255) / 256), 256, 0, stream>>>(partial, fcs_b, out);
    flag_rank<<<dim3((N_BATCH + 255) / 256), 256, 0, stream>>>(out, out, flags);
    recompute_flagged<<<dim3(N_BATCH), 256, 0, stream>>>(
        feats, w2, b2, w3, b3, w5, b5, fc1_w, fc1_b, fc2_w, fc2_b,
        fc0_w, fc0_b, fcs_w, fcs_b, flags, out);
}

// Round 2
// 6196.272 us; speedup vs baseline: 2.0407x; 1.6132x over previous
//
#include <hip/hip_runtime.h>

#define N_BATCH 32768
#define N_IMG   5
#define DIM     512
#define NKERN   200
#define DCAT    600
#define NROWS   (N_BATCH * N_IMG)   // 163840
#define EPS_FLAG 2e-4f

// ---------------------------------------------------------------------------
// Pack conv weights w[c][k][d] -> wT[kd][256], zero-padded channels 200..255.
// ---------------------------------------------------------------------------
template<int K>
__global__ void pack_wT(const float* __restrict__ w, float* __restrict__ wT) {
    int g = blockIdx.x * 256 + threadIdx.x;
    if (g >= K * 512 * 256) return;
    int kd = g >> 8, c = g & 255;
    float v = 0.f;
    if (c < NKERN) v = w[((size_t)c * K + (kd >> 9)) * 512 + (kd & 511)];
    wT[g] = v;
}

// ---------------------------------------------------------------------------
// Conv as GEMM: scores[r][c] = sum_kd feats[(r/T)*5 + r%T][kd] * wT[kd][c]
// 128x128 tile, BK=16, 8x8 micro-tile, 256 threads. Rows chunk-local.
// ---------------------------------------------------------------------------
template<int KD, int T>
__global__ __launch_bounds__(256, 4) void conv_gemm(
    const float* __restrict__ feats, const float* __restrict__ wT,
    float* __restrict__ scores, int m_base) {
    __shared__ float AsT[16][132];
    __shared__ float Bs[16][136];
    int tid = threadIdx.x;
    int tx = tid & 15, ty = tid >> 4;
    int m0l = blockIdx.x * 128, n0 = blockIdx.y * 128;
    int rr = tid >> 2, c4 = (tid & 3) * 4;
    int r0 = m_base + m0l + rr, r1 = r0 + 64;
    const float* ap0 = feats + ((size_t)(r0 / T) * 5 + (r0 % T)) * 512 + c4;
    const float* ap1 = feats + ((size_t)(r1 / T) * 5 + (r1 % T)) * 512 + c4;
    const float* bp = wT + (size_t)(tid >> 4) * 256 + n0 + (tid & 15) * 8;
    float acc[8][8] = {};

    for (int kk = 0; kk < KD; kk += 16) {
        float4 a0 = *(const float4*)(ap0 + kk);
        float4 a1 = *(const float4*)(ap1 + kk);
        const float4* bq = (const float4*)(bp + (size_t)kk * 256);
        float4 b0 = bq[0], b1 = bq[1];
        AsT[c4 + 0][rr] = a0.x; AsT[c4 + 1][rr] = a0.y;
        AsT[c4 + 2][rr] = a0.z; AsT[c4 + 3][rr] = a0.w;
        AsT[c4 + 0][rr + 64] = a1.x; AsT[c4 + 1][rr + 64] = a1.y;
        AsT[c4 + 2][rr + 64] = a1.z; AsT[c4 + 3][rr + 64] = a1.w;
        *(float4*)&Bs[tid >> 4][(tid & 15) * 8] = b0;
        *(float4*)&Bs[tid >> 4][(tid & 15) * 8 + 4] = b1;
        __syncthreads();
#pragma unroll
        for (int k2 = 0; k2 < 16; k2++) {
            float a[8], b[8];
            *(float4*)&a[0] = *(const float4*)&AsT[k2][ty * 8];
            *(float4*)&a[4] = *(const float4*)&AsT[k2][ty * 8 + 4];
            *(float4*)&b[0] = *(const float4*)&Bs[k2][tx * 8];
            *(float4*)&b[4] = *(const float4*)&Bs[k2][tx * 8 + 4];
#pragma unroll
            for (int i = 0; i < 8; i++)
#pragma unroll
                for (int j = 0; j < 8; j++)
                    acc[i][j] += a[i] * b[j];
        }
        __syncthreads();
    }
#pragma unroll
    for (int i = 0; i < 8; i++) {
        float* sp = scores + (size_t)(m0l + ty * 8 + i) * 256 + n0 + tx * 8;
        *(float4*)sp = make_float4(acc[i][0], acc[i][1], acc[i][2], acc[i][3]);
        *(float4*)(sp + 4) = make_float4(acc[i][4], acc[i][5], acc[i][6], acc[i][7]);
    }
}

// ---------------------------------------------------------------------------
// Reduce: c[n][off+ch] = relu(max_t scores[nl*T+t][ch] + bias[ch])
// ---------------------------------------------------------------------------
template<int T>
__global__ void conv_reduce(const float* __restrict__ scores,
                            const float* __restrict__ bias,
                            float* __restrict__ c, int conv_off, int n_base) {
    int g = blockIdx.x * 256 + threadIdx.x;
    int nl = g >> 8, ch = g & 255;
    if (ch >= NKERN) return;
    const float* sp = scores + (size_t)nl * T * 256 + ch;
    float m = sp[0];
#pragma unroll
    for (int t = 1; t < T; t++) m = fmaxf(m, sp[t * 256]);
    c[(size_t)(n_base + nl) * DCAT + conv_off + ch] = fmaxf(m + bias[ch], 0.f);
}

// ---------------------------------------------------------------------------
// fp32 GEMM: C = act(A@B + bias). 64x64 tile, BK=16, 4x4 micro-tile.
// (used for fc1/fc2)
// ---------------------------------------------------------------------------
template<int RELU>
__global__ __launch_bounds__(256) void gemm_bias(
    const float* __restrict__ A, const float* __restrict__ B,
    const float* __restrict__ bias, float* __restrict__ C,
    int Kd, int Nc) {
    __shared__ float AsT[16][68];
    __shared__ float Bs[16][68];
    int tid = threadIdx.x;
    int tx = tid & 15, ty = tid >> 4;
    int m0 = blockIdx.x * 64, n0 = blockIdx.y * 64;
    float acc[4][4] = {};
    int arow = tid >> 2, ac4 = tid & 3;
    int br = tid >> 4, bc = tid & 15;

    for (int kk = 0; kk < Kd; kk += 16) {
        int gk = kk + ac4 * 4;
        float4 ga = make_float4(0.f, 0.f, 0.f, 0.f);
        if (gk < Kd) ga = *(const float4*)(A + (size_t)(m0 + arow) * Kd + gk);
        AsT[ac4 * 4 + 0][arow] = ga.x;
        AsT[ac4 * 4 + 1][arow] = ga.y;
        AsT[ac4 * 4 + 2][arow] = ga.z;
        AsT[ac4 * 4 + 3][arow] = ga.w;
        float4 gb = make_float4(0.f, 0.f, 0.f, 0.f);
        int bcol = n0 + bc * 4;
        if (kk + br < Kd && bcol < Nc) gb = *(const float4*)(B + (size_t)(kk + br) * Nc + bcol);
        *(float4*)&Bs[br][bc * 4] = gb;
        __syncthreads();
#pragma unroll
        for (int k2 = 0; k2 < 16; k2++) {
            float4 a4 = *(const float4*)&AsT[k2][ty * 4];
            float4 b4 = *(const float4*)&Bs[k2][tx * 4];
            float a[4] = {a4.x, a4.y, a4.z, a4.w};
            float b[4] = {b4.x, b4.y, b4.z, b4.w};
#pragma unroll
            for (int i = 0; i < 4; i++)
#pragma unroll
                for (int j = 0; j < 4; j++)
                    acc[i][j] += a[i] * b[j];
        }
        __syncthreads();
    }
    int cb = n0 + tx * 4;
    if (cb < Nc) {
        float4 bs = *(const float4*)(bias + cb);
#pragma unroll
        for (int i = 0; i < 4; i++) {
            size_t row = m0 + ty * 4 + i;
            float4 v;
            v.x = acc[i][0] + bs.x; v.y = acc[i][1] + bs.y;
            v.z = acc[i][2] + bs.z; v.w = acc[i][3] + bs.w;
            if (RELU) {
                v.x = fmaxf(v.x, 0.f); v.y = fmaxf(v.y, 0.f);
                v.z = fmaxf(v.z, 0.f); v.w = fmaxf(v.w, 0.f);
            }
            *(float4*)(C + row * Nc + cb) = v;
        }
    }
}

// ---------------------------------------------------------------------------
// Fused fc0(+relu)+fcs: 128x128 tile, 8x8 micro, concat A, fcs-dot epilogue.
// partial[row][4] col-tile partials.
// ---------------------------------------------------------------------------
__global__ __launch_bounds__(256, 4) void fc0_fcs_128(
    const float* __restrict__ feats, const float* __restrict__ ci,
    const float* __restrict__ W, const float* __restrict__ b0,
    const float* __restrict__ fw, float* __restrict__ partial) {
    __shared__ float AsT[16][132];
    __shared__ float Bs[16][136];
    __shared__ float red[128][17];
    int tid = threadIdx.x;
    int tx = tid & 15, ty = tid >> 4;
    int m0 = blockIdx.x * 128, n0 = blockIdx.y * 128;
    int rr = tid >> 2, c4 = (tid & 3) * 4;
    int r0 = m0 + rr, r1 = r0 + 64;
    const float* af0 = feats + (size_t)r0 * 512 + c4;     // flat row n*5+img
    const float* ac0 = ci + (size_t)(r0 / 5) * 512 + c4;
    const float* af1 = feats + (size_t)r1 * 512 + c4;
    const float* ac1 = ci + (size_t)(r1 / 5) * 512 + c4;
    const float* bp = W + (size_t)(tid >> 4) * DIM + n0 + (tid & 15) * 8;
    float acc[8][8] = {};

    for (int kk = 0; kk < 1024; kk += 16) {
        float4 a0, a1;
        if (kk < 512) {
            a0 = *(const float4*)(af0 + kk);
            a1 = *(const float4*)(af1 + kk);
        } else {
            a0 = *(const float4*)(ac0 + (kk - 512));
            a1 = *(const float4*)(ac1 + (kk - 512));
        }
        const float4* bq = (const float4*)(bp + (size_t)kk * DIM);
        float4 b0v = bq[0], b1v = bq[1];
        AsT[c4 + 0][rr] = a0.x; AsT[c4 + 1][rr] = a0.y;
        AsT[c4 + 2][rr] = a0.z; AsT[c4 + 3][rr] = a0.w;
        AsT[c4 + 0][rr + 64] = a1.x; AsT[c4 + 1][rr + 64] = a1.y;
        AsT[c4 + 2][rr + 64] = a1.z; AsT[c4 + 3][rr + 64] = a1.w;
        *(float4*)&Bs[tid >> 4][(tid & 15) * 8] = b0v;
        *(float4*)&Bs[tid >> 4][(tid & 15) * 8 + 4] = b1v;
        __syncthreads();
#pragma unroll
        for (int k2 = 0; k2 < 16; k2++) {
            float a[8], b[8];
            *(float4*)&a[0] = *(const float4*)&AsT[k2][ty * 8];
            *(float4*)&a[4] = *(const float4*)&AsT[k2][ty * 8 + 4];
            *(float4*)&b[0] = *(const float4*)&Bs[k2][tx * 8];
            *(float4*)&b[4] = *(const float4*)&Bs[k2][tx * 8 + 4];
#pragma unroll
            for (int i = 0; i < 8; i++)
#pragma unroll
                for (int j = 0; j < 8; j++)
                    acc[i][j] += a[i] * b[j];
        }
        __syncthreads();
    }
    int cb = n0 + tx * 8;
    float4 ba = *(const float4*)(b0 + cb), bb = *(const float4*)(b0 + cb + 4);
    float4 fa = *(const float4*)(fw + cb), fb = *(const float4*)(fw + cb + 4);
#pragma unroll
    for (int i = 0; i < 8; i++) {
        float p = 0.f;
        p += fmaxf(acc[i][0] + ba.x, 0.f) * fa.x;
        p += fmaxf(acc[i][1] + ba.y, 0.f) * fa.y;
        p += fmaxf(acc[i][2] + ba.z, 0.f) * fa.z;
        p += fmaxf(acc[i][3] + ba.w, 0.f) * fa.w;
        p += fmaxf(acc[i][4] + bb.x, 0.f) * fb.x;
        p += fmaxf(acc[i][5] + bb.y, 0.f) * fb.y;
        p += fmaxf(acc[i][6] + bb.z, 0.f) * fb.z;
        p += fmaxf(acc[i][7] + bb.w, 0.f) * fb.w;
        red[ty * 8 + i][tx] = p;
    }
    __syncthreads();
    if (tid < 128) {
        float s = 0.f;
#pragma unroll
        for (int x = 0; x < 16; x++) s += red[tid][x];
        partial[(size_t)(m0 + tid) * 4 + blockIdx.y] = s;
    }
}

__global__ void score_finish(const float* __restrict__ partial,
                             const float* __restrict__ fcs_b,
                             float* __restrict__ out) {
    int m = blockIdx.x * 256 + threadIdx.x;
    if (m >= NROWS) return;
    float s = fcs_b[0];
#pragma unroll
    for (int q = 0; q < 4; q++) s += partial[(size_t)m * 4 + q];
    out[m] = s;
}

// ---------------------------------------------------------------------------
// Ranks from fp32 scores; flag groups with any pairwise gap < EPS_FLAG.
// ---------------------------------------------------------------------------
__global__ void flag_rank(const float* __restrict__ out_scores,
                          float* __restrict__ out, int* __restrict__ flags) {
    int n = blockIdx.x * 256 + threadIdx.x;
    if (n >= N_BATCH) return;
    float s[5];
#pragma unroll
    for (int i = 0; i < 5; i++) s[i] = out_scores[n * 5 + i];
    int f = 0;
#pragma unroll
    for (int i = 0; i < 5; i++) {
        int rk = 0;
#pragma unroll
        for (int j = 0; j < 5; j++) {
            rk += (s[j] > s[i]) || (s[j] == s[i] && j < i);
            if (j > i) f |= (fabsf(s[i] - s[j]) < EPS_FLAG);
        }
        out[NROWS + n * 5 + i] = (float)rk;
    }
    flags[n] = f;
}

// ---------------------------------------------------------------------------
// Exact f64 recompute of the full chain for flagged samples. One block/sample.
// ---------------------------------------------------------------------------
__device__ __forceinline__ double dot4d(float4 f, float4 w, double a) {
    a += (double)f.x * (double)w.x;
    a += (double)f.y * (double)w.y;
    a += (double)f.z * (double)w.z;
    a += (double)f.w * (double)w.w;
    return a;
}

__global__ __launch_bounds__(256) void recompute_flagged(
    const float* __restrict__ feats,
    const float* __restrict__ w2, const float* __restrict__ b2,
    const float* __restrict__ w3, const float* __restrict__ b3,
    const float* __restrict__ w5, const float* __restrict__ b5,
    const float* __restrict__ fc1_w, const float* __restrict__ fc1_b,
    const float* __restrict__ fc2_w, const float* __restrict__ fc2_b,
    const float* __restrict__ fc0_w, const float* __restrict__ fc0_b,
    const float* __restrict__ fcs_w, const float* __restrict__ fcs_b,
    const int* __restrict__ flags, float* __restrict__ out) {
    int n = blockIdx.x;
    if (!flags[n]) return;
    __shared__ float  fsh[2560];
    __shared__ double csh[600];
    __shared__ double hsh[600];
    __shared__ double cish[512];
    __shared__ double rred[5][4];
    int tid = threadIdx.x, lane = tid & 63, wave = tid >> 6;

    const float4* fg = (const float4*)(feats + (size_t)n * 2560);
    float4* fs4 = (float4*)fsh;
    for (int i = tid; i < 640; i += 256) fs4[i] = fg[i];
    __syncthreads();

    if (tid < 200) {
        {   // K=2, T=4
            const float* w = w2 + (size_t)tid * 1024;
            double a0 = 0.0, a1 = 0.0, a2 = 0.0, a3 = 0.0;
            for (int i = 0; i < 1024; i += 4) {
                float4 wv = *(const float4*)(w + i);
                a0 = dot4d(*(const float4*)(fsh + i),        wv, a0);
                a1 = dot4d(*(const float4*)(fsh + 512 + i),  wv, a1);
                a2 = dot4d(*(const float4*)(fsh + 1024 + i), wv, a2);
                a3 = dot4d(*(const float4*)(fsh + 1536 + i), wv, a3);
            }
            double b = (double)b2[tid];
            double m = fmax(fmax(a0, a1), fmax(a2, a3)) + b;
            csh[tid] = fmax(m, 0.0);
        }
        {   // K=3, T=3
            const float* w = w3 + (size_t)tid * 1536;
            double a0 = 0.0, a1 = 0.0, a2 = 0.0;
            for (int i = 0; i < 1536; i += 4) {
                float4 wv = *(const float4*)(w + i);
                a0 = dot4d(*(const float4*)(fsh + i),        wv, a0);
                a1 = dot4d(*(const float4*)(fsh + 512 + i),  wv, a1);
                a2 = dot4d(*(const float4*)(fsh + 1024 + i), wv, a2);
            }
            double b = (double)b3[tid];
            csh[200 + tid] = fmax(fmax(fmax(a0, a1), a2) + b, 0.0);
        }
        {   // K=5, T=1
            const float* w = w5 + (size_t)tid * 2560;
            double a0 = 0.0, a1 = 0.0, a2 = 0.0, a3 = 0.0;
            for (int i = 0; i < 2560; i += 16) {
                a0 = dot4d(*(const float4*)(fsh + i),      *(const float4*)(w + i),      a0);
                a1 = dot4d(*(const float4*)(fsh + i + 4),  *(const float4*)(w + i + 4),  a1);
                a2 = dot4d(*(const float4*)(fsh + i + 8),  *(const float4*)(w + i + 8),  a2);
                a3 = dot4d(*(const float4*)(fsh + i + 12), *(const float4*)(w + i + 12), a3);
            }
            double b = (double)b5[tid];
            csh[400 + tid] = fmax(((a0 + a1) + (a2 + a3)) + b, 0.0);
        }
    }
    __syncthreads();

#pragma unroll
    for (int c = 0; c < 3; c++) {
        int ch = tid + c * 256;
        if (ch < DCAT) {
            const float* wp = fc1_w + ch;
            double a0 = 0.0, a1 = 0.0;
            for (int k = 0; k < DCAT; k += 2) {
                a0 += csh[k]     * (double)wp[(size_t)k * DCAT];
                a1 += csh[k + 1] * (double)wp[(size_t)(k + 1) * DCAT];
            }
            hsh[ch] = fmax(a0 + a1 + (double)fc1_b[ch], 0.0);
        }
    }
    __syncthreads();

#pragma unroll
    for (int c = 0; c < 2; c++) {
        int ch = tid + c * 256;
        const float* wp = fc2_w + ch;
        double a0 = 0.0, a1 = 0.0;
        for (int k = 0; k < DCAT; k += 2) {
            a0 += hsh[k]     * (double)wp[(size_t)k * DIM];
            a1 += hsh[k + 1] * (double)wp[(size_t)(k + 1) * DIM];
        }
        cish[ch] = a0 + a1 + (double)fc2_b[ch];
    }
    __syncthreads();

    double acc0[5] = {}, acc1[5] = {};
#pragma unroll 4
    for (int k = 0; k < 512; k++) {
        double w0 = (double)fc0_w[(size_t)k * DIM + tid];
        double w1 = (double)fc0_w[(size_t)k * DIM + tid + 256];
#pragma unroll
        for (int img = 0; img < 5; img++) {
            double z = (double)fsh[img * 512 + k];
            acc0[img] += z * w0; acc1[img] += z * w1;
        }
    }
#pragma unroll 4
    for (int k = 0; k < 512; k++) {
        double w0 = (double)fc0_w[(size_t)(k + 512) * DIM + tid];
        double w1 = (double)fc0_w[(size_t)(k + 512) * DIM + tid + 256];
        double z = cish[k];
#pragma unroll
        for (int img = 0; img < 5; img++) { acc0[img] += z * w0; acc1[img] += z * w1; }
    }
    double b0a = (double)fc0_b[tid], b0b = (double)fc0_b[tid + 256];
    double fwa = (double)fcs_w[tid], fwb = (double)fcs_w[tid + 256];
#pragma unroll
    for (int img = 0; img < 5; img++) {
        double p = fmax(acc0[img] + b0a, 0.0) * fwa + fmax(acc1[img] + b0b, 0.0) * fwb;
#pragma unroll
        for (int o = 32; o >= 1; o >>= 1) p += __shfl_down(p, o, 64);
        if (lane == 0) rred[img][wave] = p;
    }
    __syncthreads();
    if (tid == 0) {
        double sc[5];
#pragma unroll
        for (int img = 0; img < 5; img++)
            sc[img] = rred[img][0] + rred[img][1] + rred[img][2] + rred[img][3]
                    + (double)fcs_b[0];
#pragma unroll
        for (int i = 0; i < 5; i++) {
            int rk = 0;
#pragma unroll
            for (int j = 0; j < 5; j++)
                rk += (sc[j] > sc[i]) || (sc[j] == sc[i] && j < i);
            out[n * 5 + i] = (float)sc[i];
            out[NROWS + n * 5 + i] = (float)rk;
        }
    }
}

// ---------------------------------------------------------------------------
// Workspace layout (bytes), ws_size >= 157,286,400 (proven by prior version):
//   c [32768][600] f32 @ 0                      : 78,643,200
//   scores @ 78,643,200                         : <= 67,108,864 (conv chunks)
//     (later reused: h [32768][600], partial [NROWS][4])
//   flags @ 87,031,808                          : 131,072   (written after
//     scores/h dead; partial spans only 2.6 MB so no collision)
//   wT @ 145,752,064                            : 5,242,880 (dead after convs;
//     overlapped later by h's tail)
// ---------------------------------------------------------------------------
extern "C" void kernel_launch(void* const* d_in, const int* in_sizes, int n_in,
                              void* d_out, int out_size, void* d_ws, size_t ws_size,
                              hipStream_t stream) {
    (void)in_sizes; (void)n_in; (void)out_size; (void)ws_size;
    const float* feats = (const float*)d_in[0];
    const float* w2    = (const float*)d_in[1];
    const float* b2    = (const float*)d_in[2];
    const float* w3    = (const float*)d_in[3];
    const float* b3    = (const float*)d_in[4];
    const float* w5    = (const float*)d_in[5];
    const float* b5    = (const float*)d_in[6];
    const float* fc1_w = (const float*)d_in[7];
    const float* fc1_b = (const float*)d_in[8];
    const float* fc2_w = (const float*)d_in[9];
    const float* fc2_b = (const float*)d_in[10];
    const float* fc0_w = (const float*)d_in[11];
    const float* fc0_b = (const float*)d_in[12];
    const float* fcs_w = (const float*)d_in[13];
    const float* fcs_b = (const float*)d_in[14];

    char* ws = (char*)d_ws;
    float* c      = (float*)ws;
    float* scores = (float*)(ws + 78643200);
    int*   flags  = (int*)(ws + 87031808);
    float* wT2    = (float*)(ws + 145752064);
    float* wT3    = wT2 + 1024 * 256;
    float* wT5    = wT3 + 1536 * 256;

    pack_wT<2><<<dim3(2 * 512), 256, 0, stream>>>(w2, wT2);
    pack_wT<3><<<dim3(3 * 512), 256, 0, stream>>>(w3, wT3);
    pack_wT<5><<<dim3(5 * 512), 256, 0, stream>>>(w5, wT5);

    // conv<2>: M=131072 rows, 2 chunks of 65536 rows (16384 samples)
    for (int chk = 0; chk < 2; chk++) {
        conv_gemm<1024, 4><<<dim3(512, 2), 256, 0, stream>>>(feats, wT2, scores, chk * 65536);
        conv_reduce<4><<<dim3(16384), 256, 0, stream>>>(scores, b2, c, 0, chk * 16384);
    }
    // conv<3>: M=98304 rows, 2 chunks of 49152 rows
    for (int chk = 0; chk < 2; chk++) {
        conv_gemm<1536, 3><<<dim3(384, 2), 256, 0, stream>>>(feats, wT3, scores, chk * 49152);
        conv_reduce<3><<<dim3(16384), 256, 0, stream>>>(scores, b3, c, 200, chk * 16384);
    }
    // conv<5>: M=32768 rows, single chunk
    conv_gemm<2560, 1><<<dim3(256, 2), 256, 0, stream>>>(feats, wT5, scores, 0);
    conv_reduce<1><<<dim3(32768), 256, 0, stream>>>(scores, b5, c, 400, 0);

    float* h = (float*)(ws + 78643200);            // overwrites scores/wT (dead)
    gemm_bias<1><<<dim3(N_BATCH / 64, 10), 256, 0, stream>>>(c, fc1_w, fc1_b, h, DCAT, DCAT);

    float* ci = (float*)ws;                        // overwrites c (dead)
    gemm_bias<0><<<dim3(N_BATCH / 64, 8), 256, 0, stream>>>(h, fc2_w, fc2_b, ci, DCAT, DIM);

    float* partial = (float*)(ws + 78643200);      // overwrites h (dead)
    fc0_fcs_128<<<dim3(NROWS / 128, 4), 256, 0, stream>>>(feats, ci, fc0_w, fc0_b, fcs_w, partial);

    float* out = (float*)d_out;
    score_finish<<<dim3(NROWS / 256), 256, 0, stream>>>(partial, fcs_b, out);
    flag_rank<<<dim3(N_BATCH / 256), 256, 0, stream>>>(out, out, flags);
    recompute_flagged<<<dim3(N_BATCH), 256, 0, stream>>>(
        feats, w2, b2, w3, b3, w5, b5, fc1_w, fc1_b, fc2_w, fc2_b,
        fc0_w, fc0_b, fcs_w, fcs_b, flags, out);
}